// Round 1
// baseline (20.561 us; speedup 1.0000x reference)
//
#include <hip/hip_runtime.h>
#include <hip/hip_bf16.h>

// Block-diagonal attention, x:[8,16,671,64] f32, blocks [0,128),[128,256),
// [256,384),[543,671) (each exactly 128 rows); gap rows [384,543) -> 0.
// One WG (256 thr = 4 waves) per (head,block); each wave owns 32 Q-rows.

typedef __attribute__((ext_vector_type(8))) short short8;   // 8 x bf16
typedef __attribute__((ext_vector_type(4))) float floatx4;  // MFMA acc

__device__ __forceinline__ unsigned short f2b(float f) {
    union { float f; unsigned u; } c; c.f = f;
    return (unsigned short)((c.u + 0x7fffu + ((c.u >> 16) & 1u)) >> 16); // RNE
}

#define XB_LD 72    // xb row stride (elems): 144B -> 2-way bank alias (free)
#define XT_LD 136   // xt row stride: 272B, 16B-aligned b128 reads
#define PL_LD 136

__global__ __launch_bounds__(256, 2)
void blockattn_kernel(const float* __restrict__ x, float* __restrict__ out)
{
    __shared__ unsigned short xb[128 * XB_LD];      // [row][k]  (Q and K)
    __shared__ unsigned short xt[64 * XT_LD];       // [e][t]    (V transposed)
    __shared__ unsigned short pl[4 * 32 * PL_LD];   // per-wave P [row][t]

    const int wg  = blockIdx.x;
    const int h   = wg >> 2;                 // b*16+n, 0..127
    const int blk = wg & 3;
    const int rowbase = (blk < 3) ? (blk << 7) : 543;
    const float* xp = x   + ((size_t)h * 671 + rowbase) * 64;
    float*       op = out + ((size_t)h * 671 + rowbase) * 64;

    const int tid = threadIdx.x;

    // ---- stage 128x64 f32 -> bf16 into xb (row-major) and xt (transposed)
    #pragma unroll
    for (int it = 0; it < 8; ++it) {
        int i4 = tid + it * 256;             // float4 index, 0..2047 (contig)
        int r  = i4 >> 4;
        int c4 = (i4 & 15) << 2;
        float4 v = *reinterpret_cast<const float4*>(xp + i4 * 4);
        unsigned short b0 = f2b(v.x), b1 = f2b(v.y), b2 = f2b(v.z), b3 = f2b(v.w);
        *reinterpret_cast<ushort4*>(&xb[r * XB_LD + c4]) = make_ushort4(b0, b1, b2, b3);
        xt[(c4 + 0) * XT_LD + r] = b0;
        xt[(c4 + 1) * XT_LD + r] = b1;
        xt[(c4 + 2) * XT_LD + r] = b2;
        xt[(c4 + 3) * XT_LD + r] = b3;
    }
    __syncthreads();

    const int lane = tid & 63;
    const int wid  = tid >> 6;
    const int l15  = lane & 15;
    const int lhi  = lane >> 4;

    // ---- S = Q K^T : 32 rows x 128 cols per wave, 16x16x32 bf16 MFMA
    floatx4 s[2][8];
    #pragma unroll
    for (int m = 0; m < 2; ++m)
        #pragma unroll
        for (int n = 0; n < 8; ++n)
            s[m][n] = (floatx4){0.f, 0.f, 0.f, 0.f};

    #pragma unroll
    for (int kk = 0; kk < 2; ++kk) {
        const int k0 = kk * 32 + lhi * 8;
        short8 a[2], b[8];
        #pragma unroll
        for (int m = 0; m < 2; ++m)
            a[m] = *reinterpret_cast<const short8*>(&xb[(wid * 32 + m * 16 + l15) * XB_LD + k0]);
        #pragma unroll
        for (int n = 0; n < 8; ++n)
            b[n] = *reinterpret_cast<const short8*>(&xb[(n * 16 + l15) * XB_LD + k0]);
        #pragma unroll
        for (int m = 0; m < 2; ++m)
            #pragma unroll
            for (int n = 0; n < 8; ++n)
                s[m][n] = __builtin_amdgcn_mfma_f32_16x16x32_bf16(a[m], b[n], s[m][n], 0, 0, 0);
    }

    #pragma unroll
    for (int m = 0; m < 2; ++m)
        #pragma unroll
        for (int n = 0; n < 8; ++n)
            s[m][n] = s[m][n] * 0.125f;      // 1/sqrt(64)

    // ---- row softmax. C layout: col = lane&15, row = (lane>>4)*4 + reg.
    // Row r is held by the 16 lanes with lane>>4 == r>>2 -> butterfly over bits 0..3.
    float rinv[2][4];
    unsigned short* plw = &pl[wid * 32 * PL_LD];
    #pragma unroll
    for (int m = 0; m < 2; ++m) {
        #pragma unroll
        for (int j = 0; j < 4; ++j) {
            float mx = s[m][0][j];
            #pragma unroll
            for (int n = 1; n < 8; ++n) mx = fmaxf(mx, s[m][n][j]);
            #pragma unroll
            for (int off = 1; off < 16; off <<= 1)
                mx = fmaxf(mx, __shfl_xor(mx, off, 64));
            float e[8];
            float sum = 0.f;
            #pragma unroll
            for (int n = 0; n < 8; ++n) { e[n] = __expf(s[m][n][j] - mx); sum += e[n]; }
            #pragma unroll
            for (int off = 1; off < 16; off <<= 1)
                sum += __shfl_xor(sum, off, 64);
            rinv[m][j] = 1.f / sum;
            const int r = m * 16 + lhi * 4 + j;
            #pragma unroll
            for (int n = 0; n < 8; ++n)
                plw[r * PL_LD + n * 16 + l15] = f2b(e[n]);   // unnormalized P
        }
    }

    // ---- O = P V : per-wave private P (no barrier needed; same-wave LDS dep)
    floatx4 o[2][4];
    #pragma unroll
    for (int m = 0; m < 2; ++m)
        #pragma unroll
        for (int n = 0; n < 4; ++n)
            o[m][n] = (floatx4){0.f, 0.f, 0.f, 0.f};

    #pragma unroll
    for (int kk = 0; kk < 4; ++kk) {
        const int t0 = kk * 32 + lhi * 8;
        short8 pa[2], vb[4];
        #pragma unroll
        for (int m = 0; m < 2; ++m)
            pa[m] = *reinterpret_cast<const short8*>(&plw[(m * 16 + l15) * PL_LD + t0]);
        #pragma unroll
        for (int n = 0; n < 4; ++n)
            vb[n] = *reinterpret_cast<const short8*>(&xt[(n * 16 + l15) * XT_LD + t0]);
        #pragma unroll
        for (int m = 0; m < 2; ++m)
            #pragma unroll
            for (int n = 0; n < 4; ++n)
                o[m][n] = __builtin_amdgcn_mfma_f32_16x16x32_bf16(pa[m], vb[n], o[m][n], 0, 0, 0);
    }

    // ---- epilogue: normalize by rowsum (rinv already in matching lanes/regs)
    #pragma unroll
    for (int m = 0; m < 2; ++m)
        #pragma unroll
        for (int n = 0; n < 4; ++n)
            #pragma unroll
            for (int j = 0; j < 4; ++j) {
                const int r = wid * 32 + m * 16 + lhi * 4 + j;
                op[r * 64 + n * 16 + l15] = o[m][n][j] * rinv[m][j];
            }
}

// rows [384,543) of every (b,n): output = 0
__global__ void zero_gap_kernel(float* __restrict__ out)
{
    const int TOT = 128 * 159 * 16;          // float4 count
    int i = blockIdx.x * 256 + threadIdx.x;
    if (i >= TOT) return;
    int h   = i / (159 * 16);
    int rem = i - h * (159 * 16);
    int r   = rem >> 4;
    int c   = rem & 15;
    *reinterpret_cast<float4*>(out + ((size_t)h * 671 + 384 + r) * 64 + (c << 2)) =
        make_float4(0.f, 0.f, 0.f, 0.f);
}

extern "C" void kernel_launch(void* const* d_in, const int* in_sizes, int n_in,
                              void* d_out, int out_size, void* d_ws, size_t ws_size,
                              hipStream_t stream)
{
    const float* x  = (const float*)d_in[0];
    float* out      = (float*)d_out;
    hipLaunchKernelGGL(zero_gap_kernel, dim3((128 * 159 * 16 + 255) / 256), dim3(256), 0, stream, out);
    hipLaunchKernelGGL(blockattn_kernel, dim3(512), dim3(256), 0, stream, x, out);
}

// Round 2
// 15.077 us; speedup vs baseline: 1.3637x; 1.3637x over previous
//
#include <hip/hip_runtime.h>
#include <hip/hip_bf16.h>

// Block-diagonal attention, x:[8,16,671,64] f32, blocks [0,128),[128,256),
// [256,384),[543,671); gap rows [384,543) -> 0.
// One WG (256 thr = 4 waves) per (head,block); wave owns 32 q-rows.
// Swapped QK^T (S^T = mfma(K,Q)) -> in-lane softmax -> in-register P
// redistribution via cvt_pk_bf16 + permlane{32,16}_swap -> PV -> f4 stores.

typedef __attribute__((ext_vector_type(8))) short short8;   // 8 x bf16
typedef __attribute__((ext_vector_type(4))) float floatx4;  // MFMA acc
typedef __attribute__((ext_vector_type(4))) int intx4;
typedef __attribute__((ext_vector_type(2))) unsigned int uint2v;

__device__ __forceinline__ unsigned short f2b(float f) {
    union { float f; unsigned u; } c; c.f = f;
    return (unsigned short)((c.u + 0x7fffu + ((c.u >> 16) & 1u)) >> 16); // RNE
}

__device__ __forceinline__ int cvt_pk_bf16(float lo, float hi) {
    int r;
    asm("v_cvt_pk_bf16_f32 %0, %1, %2" : "=v"(r) : "v"(lo), "v"(hi));
    return r;
}

// [X,Y] -> (r0, r1) with r0 = [X.g0, X.g2, Y.g0, Y.g2], r1 = [X.g1, X.g3, Y.g1, Y.g3]
// (g = 16-lane group). r0/r1 are exactly the PV B-frag words (see derivation).
__device__ __forceinline__ uint2v dswap(unsigned a, unsigned b) {
    uint2v t = __builtin_amdgcn_permlane32_swap(a, b, false, false);
    return __builtin_amdgcn_permlane16_swap(t[0], t[1], false, false);
}

#define XB_LD 72    // row stride (ushort): 144B -> uniform banks for b128 reads
#define XT_LD 136   // 272B stride: 16B-aligned b128, conflict-free R/W

__global__ __launch_bounds__(256, 4)
void blockattn_kernel(const float* __restrict__ x, float* __restrict__ out)
{
    __shared__ __align__(16) unsigned short xb[128 * XB_LD]; // [t][k] K/Q, 18.4KB
    __shared__ __align__(16) unsigned short xt[64 * XT_LD];  // [e][t] V^T, 17.4KB

    const int wg  = blockIdx.x;
    const int h   = wg >> 2;
    const int blk = wg & 3;
    const int rowbase = (blk < 3) ? (blk << 7) : 543;
    const float* xp = x   + ((size_t)h * 671 + rowbase) * 64;
    float*       op = out + ((size_t)h * 671 + rowbase) * 64;

    const int tid  = threadIdx.x;
    const int lane = tid & 63;
    const int wid  = tid >> 6;

    // ---- pass A: coalesced float4 loads (feeds xb row-major)
    float4 va[8];
    #pragma unroll
    for (int it = 0; it < 8; ++it)
        va[it] = *reinterpret_cast<const float4*>(xp + (tid + it * 256) * 4);

    // ---- pass B: coalesced dword column-gather (feeds xt transposed)
    // thread: e = lane, t-chunks c = wid + 4*it2 (rows 8c..8c+7)
    float vbf[32];
    #pragma unroll
    for (int it2 = 0; it2 < 4; ++it2) {
        const int c = wid + it2 * 4;
        #pragma unroll
        for (int j = 0; j < 8; ++j)
            vbf[it2 * 8 + j] = xp[(c * 8 + j) * 64 + lane];
    }

    // ---- fused gap zero: rows [384,543) of this h (blk==3 WGs), overlaps loads
    if (blk == 3) {
        float* gp = out + ((size_t)h * 671 + 384) * 64;
        #pragma unroll
        for (int it = 0; it < 10; ++it) {
            int i4 = tid + it * 256;
            if (i4 < 159 * 16)
                *reinterpret_cast<float4*>(gp + i4 * 4) = make_float4(0.f, 0.f, 0.f, 0.f);
        }
    }

    // ---- convert + LDS writes (conflict-free both sides)
    #pragma unroll
    for (int it = 0; it < 8; ++it) {
        int i4 = tid + it * 256;
        int r = i4 >> 4, c4 = (i4 & 15) << 2;
        *reinterpret_cast<ushort4*>(&xb[r * XB_LD + c4]) =
            make_ushort4(f2b(va[it].x), f2b(va[it].y), f2b(va[it].z), f2b(va[it].w));
    }
    #pragma unroll
    for (int it2 = 0; it2 < 4; ++it2) {
        const int c = wid + it2 * 4;
        short8 w;
        #pragma unroll
        for (int j = 0; j < 8; ++j)
            w[j] = (short)f2b(vbf[it2 * 8 + j]);
        *reinterpret_cast<short8*>(&xt[lane * XT_LD + c * 8]) = w;  // bank-uniform b128
    }
    __syncthreads();

    const int l15 = lane & 15;
    const int lhi = lane >> 4;
    const int k0a = lhi * 8;

    // ---- S^T = K · Q : tiles [t=8][q=2], C layout: row=t-part, col=q-part
    short8 bq[2][2];   // Q rows (B operand)
    #pragma unroll
    for (int nq = 0; nq < 2; ++nq)
        #pragma unroll
        for (int kk = 0; kk < 2; ++kk)
            bq[nq][kk] = *reinterpret_cast<const short8*>(
                &xb[(wid * 32 + nq * 16 + l15) * XB_LD + kk * 32 + k0a]);

    floatx4 sT[8][2];
    #pragma unroll
    for (int mt = 0; mt < 8; ++mt)
        #pragma unroll
        for (int nq = 0; nq < 2; ++nq)
            sT[mt][nq] = (floatx4){0.f, 0.f, 0.f, 0.f};

    #pragma unroll
    for (int mt = 0; mt < 8; ++mt) {
        short8 ak[2];
        #pragma unroll
        for (int kk = 0; kk < 2; ++kk)
            ak[kk] = *reinterpret_cast<const short8*>(
                &xb[(mt * 16 + l15) * XB_LD + kk * 32 + k0a]);
        #pragma unroll
        for (int nq = 0; nq < 2; ++nq)
            #pragma unroll
            for (int kk = 0; kk < 2; ++kk)
                sT[mt][nq] = __builtin_amdgcn_mfma_f32_16x16x32_bf16(ak[kk], bq[nq][kk], sT[mt][nq], 0, 0, 0);
    }

    // ---- softmax, fully in-lane + 2 shuffles; pack P to bf16 pairs in regs.
    // Lane (lhi,l15): sT[mt][nq][j] = S[q=16nq+l15 (+wid*32)][t=16mt+4*lhi+j]
    const float C2 = 0.125f * 1.44269504088896340736f;  // scale * log2(e)
    int   pk[8][2][2];
    float rinv[2];
    #pragma unroll
    for (int nq = 0; nq < 2; ++nq) {
        float mx = sT[0][nq][0];
        #pragma unroll
        for (int mt = 0; mt < 8; ++mt)
            #pragma unroll
            for (int j = 0; j < 4; ++j)
                mx = fmaxf(mx, sT[mt][nq][j]);
        mx = fmaxf(mx, __shfl_xor(mx, 16, 64));
        mx = fmaxf(mx, __shfl_xor(mx, 32, 64));
        float sum = 0.f;
        #pragma unroll
        for (int mt = 0; mt < 8; ++mt) {
            float e0 = exp2f((sT[mt][nq][0] - mx) * C2);
            float e1 = exp2f((sT[mt][nq][1] - mx) * C2);
            float e2 = exp2f((sT[mt][nq][2] - mx) * C2);
            float e3 = exp2f((sT[mt][nq][3] - mx) * C2);
            sum += (e0 + e1) + (e2 + e3);
            pk[mt][nq][0] = cvt_pk_bf16(e0, e1);
            pk[mt][nq][1] = cvt_pk_bf16(e2, e3);
        }
        sum += __shfl_xor(sum, 16, 64);
        sum += __shfl_xor(sum, 32, 64);
        rinv[nq] = 1.f / sum;
    }

    // ---- O^T = V^T · P^T : A from xt, B built in-register via 2 permlane swaps
    floatx4 oT[4][2];
    #pragma unroll
    for (int ne = 0; ne < 4; ++ne)
        #pragma unroll
        for (int nq = 0; nq < 2; ++nq)
            oT[ne][nq] = (floatx4){0.f, 0.f, 0.f, 0.f};

    #pragma unroll
    for (int kk = 0; kk < 4; ++kk) {
        short8 pb[2];
        #pragma unroll
        for (int nq = 0; nq < 2; ++nq) {
            uint2v rA = dswap((unsigned)pk[2 * kk][nq][0], (unsigned)pk[2 * kk + 1][nq][0]);
            uint2v rB = dswap((unsigned)pk[2 * kk][nq][1], (unsigned)pk[2 * kk + 1][nq][1]);
            union { intx4 i; short8 s; } u;
            u.i = (intx4){(int)rA[0], (int)rB[0], (int)rA[1], (int)rB[1]};
            pb[nq] = u.s;
        }
        #pragma unroll
        for (int ne = 0; ne < 4; ++ne) {
            short8 av = *reinterpret_cast<const short8*>(
                &xt[(ne * 16 + l15) * XT_LD + kk * 32 + k0a]);
            #pragma unroll
            for (int nq = 0; nq < 2; ++nq)
                oT[ne][nq] = __builtin_amdgcn_mfma_f32_16x16x32_bf16(av, pb[nq], oT[ne][nq], 0, 0, 0);
        }
    }

    // ---- epilogue: O[q][e], lane holds 4 consecutive e -> float4 stores
    #pragma unroll
    for (int ne = 0; ne < 4; ++ne)
        #pragma unroll
        for (int nq = 0; nq < 2; ++nq) {
            const int q = wid * 32 + nq * 16 + l15;
            float4 v = make_float4(oT[ne][nq][0] * rinv[nq], oT[ne][nq][1] * rinv[nq],
                                   oT[ne][nq][2] * rinv[nq], oT[ne][nq][3] * rinv[nq]);
            *reinterpret_cast<float4*>(&op[q * 64 + ne * 16 + lhi * 4]) = v;
        }
}

extern "C" void kernel_launch(void* const* d_in, const int* in_sizes, int n_in,
                              void* d_out, int out_size, void* d_ws, size_t ws_size,
                              hipStream_t stream)
{
    const float* x = (const float*)d_in[0];
    float* out     = (float*)d_out;
    hipLaunchKernelGGL(blockattn_kernel, dim3(512), dim3(256), 0, stream, x, out);
}

// Round 6
// 14.817 us; speedup vs baseline: 1.3877x; 1.0176x over previous
//
#include <hip/hip_runtime.h>
#include <hip/hip_bf16.h>

// Block-diagonal attention, x:[8,16,671,64] f32, blocks [0,128),[128,256),
// [256,384),[543,671); gap rows [384,543) -> 0.
// One WG (512 thr = 8 waves) per (head,block); wave owns 16 q-rows.
// Swapped QK^T (S^T = mfma(K,Q)) -> in-lane softmax -> in-register P via
// cvt_pk_bf16 + permlane{32,16}_swap -> PV -> float4 stores.
// V^T (xt) built by LDS->LDS transpose from xb, overlapped with QK^T.

typedef __attribute__((ext_vector_type(8))) short short8;   // 8 x bf16
typedef __attribute__((ext_vector_type(4))) float floatx4;  // MFMA acc
typedef __attribute__((ext_vector_type(4))) int intx4;
typedef __attribute__((ext_vector_type(2))) unsigned int uint2v;

__device__ __forceinline__ unsigned short f2b(float f) {
    union { float f; unsigned u; } c; c.f = f;
    return (unsigned short)((c.u + 0x7fffu + ((c.u >> 16) & 1u)) >> 16); // RNE
}

__device__ __forceinline__ int cvt_pk_bf16(float lo, float hi) {
    int r;
    asm("v_cvt_pk_bf16_f32 %0, %1, %2" : "=v"(r) : "v"(lo), "v"(hi));
    return r;
}

// [X,Y] -> (r0, r1), r0 = [X.g0, X.g2, Y.g0, Y.g2], r1 = [X.g1, X.g3, Y.g1, Y.g3]
// (g = 16-lane group) — exactly the PV B-frag words.
__device__ __forceinline__ uint2v dswap(unsigned a, unsigned b) {
    uint2v t = __builtin_amdgcn_permlane32_swap(a, b, false, false);
    return __builtin_amdgcn_permlane16_swap(t[0], t[1], false, false);
}

#define XB_LD 72    // row stride (ushort): 144B -> conflict-free b128 R/W
#define XT_LD 136   // 272B stride: 16B-aligned b128, conflict-free R/W

__global__ __launch_bounds__(512, 4)
void blockattn_kernel(const float* __restrict__ x, float* __restrict__ out)
{
    __shared__ __align__(16) unsigned short xb[128 * XB_LD]; // [t][k] K/Q, 18.4KB
    __shared__ __align__(16) unsigned short xt[64 * XT_LD];  // [e][t] V^T, 17.4KB

    const int wg  = blockIdx.x;
    const int h   = wg >> 2;
    const int blk = wg & 3;
    const int rowbase = (blk < 3) ? (blk << 7) : 543;
    const float* xp = x   + ((size_t)h * 671 + rowbase) * 64;
    float*       op = out + ((size_t)h * 671 + rowbase) * 64;

    const int tid  = threadIdx.x;
    const int lane = tid & 63;
    const int wid  = tid >> 6;          // 0..7

    // ---- stage: coalesced float4 loads (whole 128x64 block, one pass)
    float4 va[4];
    #pragma unroll
    for (int it = 0; it < 4; ++it)
        va[it] = *reinterpret_cast<const float4*>(xp + (tid + it * 512) * 4);

    // ---- fused gap zero (blk==3 WGs), overlaps load latency
    if (blk == 3) {
        float* gp = out + ((size_t)h * 671 + 384) * 64;
        #pragma unroll
        for (int it = 0; it < 5; ++it) {
            int i4 = tid + it * 512;
            if (i4 < 159 * 16)
                *reinterpret_cast<float4*>(gp + i4 * 4) = make_float4(0.f, 0.f, 0.f, 0.f);
        }
    }

    // ---- convert f32->bf16, write xb row-major
    #pragma unroll
    for (int it = 0; it < 4; ++it) {
        int i4 = tid + it * 512;
        int r = i4 >> 4, c4 = (i4 & 15) << 2;
        *reinterpret_cast<ushort4*>(&xb[r * XB_LD + c4]) =
            make_ushort4(f2b(va[it].x), f2b(va[it].y), f2b(va[it].z), f2b(va[it].w));
    }
    __syncthreads();

    const int l15 = lane & 15;
    const int lhi = lane >> 4;
    const int k0a = lhi * 8;

    // ---- S^T = K · Q : this wave's 16 q-rows, C: row=t-part, col=q-part
    short8 bq[2];
    #pragma unroll
    for (int kk = 0; kk < 2; ++kk)
        bq[kk] = *reinterpret_cast<const short8*>(
            &xb[(wid * 16 + l15) * XB_LD + kk * 32 + k0a]);

    floatx4 sT[8];
    #pragma unroll
    for (int mt = 0; mt < 8; ++mt)
        sT[mt] = (floatx4){0.f, 0.f, 0.f, 0.f};

    #pragma unroll
    for (int mt = 0; mt < 8; ++mt) {
        short8 ak[2];
        #pragma unroll
        for (int kk = 0; kk < 2; ++kk)
            ak[kk] = *reinterpret_cast<const short8*>(
                &xb[(mt * 16 + l15) * XB_LD + kk * 32 + k0a]);
        #pragma unroll
        for (int kk = 0; kk < 2; ++kk)
            sT[mt] = __builtin_amdgcn_mfma_f32_16x16x32_bf16(ak[kk], bq[kk], sT[mt], 0, 0, 0);
    }

    // ---- build xt = V^T via LDS->LDS transpose (overlaps with MFMA above)
    // thread: e = lane, t-chunks c = wid + 8*it2; column reads are 2 lanes/bank (free)
    #pragma unroll
    for (int it2 = 0; it2 < 2; ++it2) {
        const int c = wid + it2 * 8;
        short8 w;
        #pragma unroll
        for (int j = 0; j < 8; ++j)
            w[j] = (short)xb[(c * 8 + j) * XB_LD + lane];
        *reinterpret_cast<short8*>(&xt[lane * XT_LD + c * 8]) = w;
    }

    // ---- softmax: in-lane over 32 vals + 2 shuffles; pack P to bf16 in regs
    // Lane (lhi,l15): sT[mt][j] = S[q=wid*16+l15][t=16mt+4*lhi+j]
    const float C2 = 0.125f * 1.44269504088896340736f;  // scale * log2(e)
    int   pk[8][2];
    float rinv;
    {
        float mx = sT[0][0];
        #pragma unroll
        for (int mt = 0; mt < 8; ++mt)
            #pragma unroll
            for (int j = 0; j < 4; ++j)
                mx = fmaxf(mx, sT[mt][j]);
        mx = fmaxf(mx, __shfl_xor(mx, 16, 64));
        mx = fmaxf(mx, __shfl_xor(mx, 32, 64));
        float sum = 0.f;
        #pragma unroll
        for (int mt = 0; mt < 8; ++mt) {
            float e0 = exp2f((sT[mt][0] - mx) * C2);
            float e1 = exp2f((sT[mt][1] - mx) * C2);
            float e2 = exp2f((sT[mt][2] - mx) * C2);
            float e3 = exp2f((sT[mt][3] - mx) * C2);
            sum += (e0 + e1) + (e2 + e3);
            pk[mt][0] = cvt_pk_bf16(e0, e1);
            pk[mt][1] = cvt_pk_bf16(e2, e3);
        }
        sum += __shfl_xor(sum, 16, 64);
        sum += __shfl_xor(sum, 32, 64);
        rinv = 1.f / sum;
    }
    __syncthreads();   // xt complete before PV reads

    // ---- O^T = V^T · P^T : A from xt, B built via 2 permlane swaps
    floatx4 oT[4];
    #pragma unroll
    for (int ne = 0; ne < 4; ++ne)
        oT[ne] = (floatx4){0.f, 0.f, 0.f, 0.f};

    #pragma unroll
    for (int kk = 0; kk < 4; ++kk) {
        uint2v rA = dswap((unsigned)pk[2 * kk][0], (unsigned)pk[2 * kk + 1][0]);
        uint2v rB = dswap((unsigned)pk[2 * kk][1], (unsigned)pk[2 * kk + 1][1]);
        union { intx4 i; short8 s; } u;
        u.i = (intx4){(int)rA[0], (int)rB[0], (int)rA[1], (int)rB[1]};
        short8 pb = u.s;
        #pragma unroll
        for (int ne = 0; ne < 4; ++ne) {
            short8 av = *reinterpret_cast<const short8*>(
                &xt[(ne * 16 + l15) * XT_LD + kk * 32 + k0a]);
            oT[ne] = __builtin_amdgcn_mfma_f32_16x16x32_bf16(av, pb, oT[ne], 0, 0, 0);
        }
    }

    // ---- epilogue: O[q][e], lane holds 4 consecutive e -> float4 stores
    const int q = wid * 16 + l15;
    #pragma unroll
    for (int ne = 0; ne < 4; ++ne) {
        float4 v = make_float4(oT[ne][0] * rinv, oT[ne][1] * rinv,
                               oT[ne][2] * rinv, oT[ne][3] * rinv);
        *reinterpret_cast<float4*>(&op[q * 64 + ne * 16 + lhi * 4]) = v;
    }
}

extern "C" void kernel_launch(void* const* d_in, const int* in_sizes, int n_in,
                              void* d_out, int out_size, void* d_ws, size_t ws_size,
                              hipStream_t stream)
{
    const float* x = (const float*)d_in[0];
    float* out     = (float*)d_out;
    hipLaunchKernelGGL(blockattn_kernel, dim3(512), dim3(512), 0, stream, x, out);
}